// Round 4
// baseline (546.011 us; speedup 1.0000x reference)
//
#include <hip/hip_runtime.h>
#include <hip/hip_fp16.h>
#include <math.h>

#define N 4096
#define TPB 256
#define PI2_F 6.283185307179586f
#define PAD(i) ((i) + ((i) >> 4))   // bank-spread for 4B LDS elements

__device__ __forceinline__ float2 cmul(float2 a, float2 b) {
    return make_float2(a.x * b.x - a.y * b.y, a.x * b.y + a.y * b.x);
}
__device__ __forceinline__ float2 cadd(float2 a, float2 b) { return make_float2(a.x + b.x, a.y + b.y); }
__device__ __forceinline__ float2 csub(float2 a, float2 b) { return make_float2(a.x - b.x, a.y - b.y); }
__device__ __forceinline__ float2 muli(float2 a) { return make_float2(-a.y, a.x); }   // +i * a (inverse)

// fast atan2: poly on t in [0,1], max err ~1e-5 rad.
__device__ __forceinline__ float fast_atan2f(float y, float x) {
    float ax = fabsf(x), ay = fabsf(y);
    float mx = fmaxf(ax, ay), mn = fminf(ax, ay);
    float t = mn * __builtin_amdgcn_rcpf(fmaxf(mx, 1e-37f));
    float s = t * t;
    float r = fmaf(s, fmaf(s, fmaf(s, fmaf(s, 0.0208351f, -0.0851330f),
                                    0.1801410f), -0.3302995f), 0.9998660f) * t;
    if (ay > ax) r = 1.5707963267948966f - r;
    if (x < 0.0f) r = 3.1415926535897932f - r;
    return copysignf(r, y);
}

// 16-point inverse DFT, in-place, natural order. Two radix-4 stages.
__device__ __forceinline__ void ifft16(float2 v[16]) {
    const float C1 = 0.9238795325112867f, S1 = 0.3826834323650898f;
    const float C2 = 0.7071067811865476f;
    float2 y[16];
    #pragma unroll
    for (int t = 0; t < 4; ++t) {
        float2 a0 = v[t], a1 = v[t + 4], a2 = v[t + 8], a3 = v[t + 12];
        float2 t0 = cadd(a0, a2), t1 = csub(a0, a2);
        float2 t2 = cadd(a1, a3), t3 = muli(csub(a1, a3));
        float2 c0 = cadd(t0, t2), c1 = cadd(t1, t3);
        float2 c2 = csub(t0, t2), c3 = csub(t1, t3);
        if (t == 0) {
            y[0] = c0; y[1] = c1; y[2] = c2; y[3] = c3;
        } else if (t == 1) {
            y[4] = c0;
            y[5] = cmul(c1, make_float2(C1, S1));
            y[6] = cmul(c2, make_float2(C2, C2));
            y[7] = cmul(c3, make_float2(S1, C1));
        } else if (t == 2) {
            y[8] = c0;
            y[9]  = cmul(c1, make_float2(C2, C2));
            y[10] = muli(c2);
            y[11] = cmul(c3, make_float2(-C2, C2));
        } else {
            y[12] = c0;
            y[13] = cmul(c1, make_float2(S1, C1));
            y[14] = cmul(c2, make_float2(-C2, C2));
            y[15] = cmul(c3, make_float2(-C1, -S1));
        }
    }
    #pragma unroll
    for (int t = 0; t < 4; ++t) {
        float2 a0 = y[t], a1 = y[t + 4], a2 = y[t + 8], a3 = y[t + 12];
        float2 t0 = cadd(a0, a2), t1 = csub(a0, a2);
        float2 t2 = cadd(a1, a3), t3 = muli(csub(a1, a3));
        v[t]      = cadd(t0, t2);
        v[t + 4]  = cadd(t1, t3);
        v[t + 8]  = csub(t0, t2);
        v[t + 12] = csub(t1, t3);
    }
}

// ---------------------------------------------------------------------------
// Pass 1: fused (mag/phase -> complex) + 4096-pt row inverse FFT.
// fp16 LDS exchanges (17 KB -> 8 blocks/CU). Output half2, scaled 1/4096.
// ---------------------------------------------------------------------------
__global__ __launch_bounds__(TPB, 8) void k_fft_rows_fused(
    const float* __restrict__ xr, const float* __restrict__ xi,
    const float* __restrict__ mk, const float* __restrict__ pk,
    __half2* __restrict__ out)
{
    __shared__ __half2 lds[4096 + 256];
    const int t = threadIdx.x;
    const size_t base = (size_t)blockIdx.x * N;
    float2 v[16];

    #pragma unroll
    for (int q = 0; q < 16; ++q) {
        int idx = t + 256 * q;
        float a = xr[base + idx];
        float b = xi[base + idx];
        float mag = sqrtf(a * a + b * b) * mk[base + idx];
        float ph  = fast_atan2f(b, a) * pk[base + idx];
        float s, c;
        __sincosf(ph, &s, &c);
        v[q] = make_float2(mag * c, mag * s);
    }

    // stage 0: m=1, j=t, twiddle W4096^{p*t}, dst = 16t+p
    ifft16(v);
    {
        float s1, c1;
        __sincosf(PI2_F * (float)t * (1.0f / 4096.0f), &s1, &c1);
        float2 w1 = make_float2(c1, s1);
        float2 w = make_float2(1.0f, 0.0f);
        #pragma unroll
        for (int p = 0; p < 16; ++p) {
            float2 z = cmul(v[p], w);
            lds[PAD(16 * t + p)] = __floats2half2_rn(z.x, z.y);
            w = cmul(w, w1);
        }
    }
    __syncthreads();
    #pragma unroll
    for (int q = 0; q < 16; ++q) v[q] = __half22float2(lds[PAD(t + 256 * q)]);
    __syncthreads();

    // stage 1: m=16, j=t>>4, k=t&15, twiddle W256^{p*j}, dst = j*256+k+16p
    ifft16(v);
    {
        int j = t >> 4, k = t & 15;
        float s1, c1;
        __sincosf(PI2_F * (float)j * (1.0f / 256.0f), &s1, &c1);
        float2 w1 = make_float2(c1, s1);
        float2 w = make_float2(1.0f, 0.0f);
        int dbase = j * 256 + k;
        #pragma unroll
        for (int p = 0; p < 16; ++p) {
            float2 z = cmul(v[p], w);
            lds[PAD(dbase + 16 * p)] = __floats2half2_rn(z.x, z.y);
            w = cmul(w, w1);
        }
    }
    __syncthreads();
    #pragma unroll
    for (int q = 0; q < 16; ++q) v[q] = __half22float2(lds[PAD(t + 256 * q)]);

    // stage 2: m=256, no twiddle, dst = t + 256p
    ifft16(v);
    const float S = 1.0f / 4096.0f;
    #pragma unroll
    for (int p = 0; p < 16; ++p)
        out[base + t + 256 * p] = __floats2half2_rn(v[p].x * S, v[p].y * S);
}

// ---------------------------------------------------------------------------
// Tiled transpose of 4096x4096 half2 (4-byte elements)
// ---------------------------------------------------------------------------
__global__ void k_transpose(const unsigned int* __restrict__ in,
                            unsigned int* __restrict__ out)
{
    __shared__ unsigned int tile[32][33];
    const int bx = blockIdx.x * 32, by = blockIdx.y * 32;
    const int tx = threadIdx.x, ty = threadIdx.y;   // block (32,8)
    #pragma unroll
    for (int k = 0; k < 4; ++k)
        tile[ty + k * 8][tx] = in[(size_t)(by + ty + k * 8) * N + bx + tx];
    __syncthreads();
    #pragma unroll
    for (int k = 0; k < 4; ++k)
        out[(size_t)(bx + ty + k * 8) * N + by + tx] = tile[tx][ty + k * 8];
}

// ---------------------------------------------------------------------------
// Pass 2: row FFT on transposed half2 array (= column FFT); real part out
// (fp16) with ifftshift sign (-1)^(row+t) and the second 1/4096 scale.
// ---------------------------------------------------------------------------
__global__ __launch_bounds__(TPB, 8) void k_fft_rows_final(
    const __half2* __restrict__ in, __half* __restrict__ out)
{
    __shared__ __half2 lds[4096 + 256];
    const int t = threadIdx.x;
    const int row = blockIdx.x;
    const size_t base = (size_t)row * N;
    float2 v[16];

    #pragma unroll
    for (int q = 0; q < 16; ++q) v[q] = __half22float2(in[base + t + 256 * q]);

    ifft16(v);
    {
        float s1, c1;
        __sincosf(PI2_F * (float)t * (1.0f / 4096.0f), &s1, &c1);
        float2 w1 = make_float2(c1, s1);
        float2 w = make_float2(1.0f, 0.0f);
        #pragma unroll
        for (int p = 0; p < 16; ++p) {
            float2 z = cmul(v[p], w);
            lds[PAD(16 * t + p)] = __floats2half2_rn(z.x, z.y);
            w = cmul(w, w1);
        }
    }
    __syncthreads();
    #pragma unroll
    for (int q = 0; q < 16; ++q) v[q] = __half22float2(lds[PAD(t + 256 * q)]);
    __syncthreads();

    ifft16(v);
    {
        int j = t >> 4, k = t & 15;
        float s1, c1;
        __sincosf(PI2_F * (float)j * (1.0f / 256.0f), &s1, &c1);
        float2 w1 = make_float2(c1, s1);
        float2 w = make_float2(1.0f, 0.0f);
        int dbase = j * 256 + k;
        #pragma unroll
        for (int p = 0; p < 16; ++p) {
            float2 z = cmul(v[p], w);
            lds[PAD(dbase + 16 * p)] = __floats2half2_rn(z.x, z.y);
            w = cmul(w, w1);
        }
    }
    __syncthreads();
    #pragma unroll
    for (int q = 0; q < 16; ++q) v[q] = __half22float2(lds[PAD(t + 256 * q)]);

    ifft16(v);

    const float scale = 1.0f / 4096.0f;
    const float sgn = ((row + t) & 1) ? -scale : scale;
    #pragma unroll
    for (int p = 0; p < 16; ++p)
        out[base + t + 256 * p] = __float2half_rn(v[p].x * sgn);
}

// ---------------------------------------------------------------------------
// Conv + BN + PReLU (transposed taps). Layer 0 reads fp16 image.
// ---------------------------------------------------------------------------
__device__ __forceinline__ float bn_prelu(float acc,
    const float* __restrict__ cb, const float* __restrict__ bg,
    const float* __restrict__ bb, const float* __restrict__ bm,
    const float* __restrict__ bv, const float* __restrict__ pa, int layer)
{
    float g  = bg[layer];
    float rs = rsqrtf(bv[layer] + 1e-5f);
    float v = (acc + cb[layer]) * (g * rs) + (bb[layer] - g * bm[layer] * rs);
    float a = pa[layer];
    return v >= 0.0f ? v : a * v;
}

__global__ void k_conv_h0(const __half* __restrict__ in, float* __restrict__ out,
                          const float* __restrict__ cw, const float* __restrict__ cb,
                          const float* __restrict__ bg, const float* __restrict__ bb,
                          const float* __restrict__ bm, const float* __restrict__ bv,
                          const float* __restrict__ pa)
{
    const int wout = 1365, win = 4096;
    int idx = blockIdx.x * blockDim.x + threadIdx.x;
    if (idx >= wout * wout) return;
    int r = idx / wout, c = idx % wout;
    const float* w = cw;
    float acc = 0.0f;
    #pragma unroll
    for (int di = 0; di < 3; ++di)
        #pragma unroll
        for (int dj = 0; dj < 3; ++dj)
            acc += __half2float(in[(size_t)(3 * r + dj) * win + (3 * c + di)]) * w[di * 3 + dj];
    out[idx] = bn_prelu(acc, cb, bg, bb, bm, bv, pa, 0);
}

__global__ void k_conv(const float* __restrict__ in, float* __restrict__ out,
                       int win, int wout,
                       const float* __restrict__ cw, const float* __restrict__ cb,
                       const float* __restrict__ bg, const float* __restrict__ bb,
                       const float* __restrict__ bm, const float* __restrict__ bv,
                       const float* __restrict__ pa, int layer)
{
    int idx = blockIdx.x * blockDim.x + threadIdx.x;
    if (idx >= wout * wout) return;
    int r = idx / wout, c = idx % wout;
    const float* w = cw + layer * 9;
    float acc = 0.0f;
    #pragma unroll
    for (int di = 0; di < 3; ++di)
        #pragma unroll
        for (int dj = 0; dj < 3; ++dj)
            acc += in[(size_t)(3 * r + dj) * win + (3 * c + di)] * w[di * 3 + dj];
    out[idx] = bn_prelu(acc, cb, bg, bb, bm, bv, pa, layer);
}

// ---------------------------------------------------------------------------
// Tail: conv4 (151->50) + conv5 (50->16) + head, one block of 1024 threads.
// ---------------------------------------------------------------------------
__global__ __launch_bounds__(1024) void k_tail(
    const float* __restrict__ c3img,
    const float* __restrict__ cw, const float* __restrict__ cb,
    const float* __restrict__ bg, const float* __restrict__ bb,
    const float* __restrict__ bm, const float* __restrict__ bv,
    const float* __restrict__ pa,
    const float* __restrict__ w5, const float* __restrict__ b5,
    const float* __restrict__ lg, const float* __restrict__ lb,
    const float* __restrict__ p5a,
    const float* __restrict__ w6, const float* __restrict__ b6,
    float* __restrict__ out)
{
    __shared__ float s4[2500];
    __shared__ float s5[256];
    __shared__ float sx[256];
    __shared__ float h[82];
    __shared__ float red[2];
    const int tid = threadIdx.x;

    for (int idx = tid; idx < 2500; idx += 1024) {
        int r = idx / 50, c = idx % 50;
        const float* w = cw + 3 * 9;
        float acc = 0.0f;
        #pragma unroll
        for (int di = 0; di < 3; ++di)
            #pragma unroll
            for (int dj = 0; dj < 3; ++dj)
                acc += c3img[(size_t)(3 * r + dj) * 151 + (3 * c + di)] * w[di * 3 + dj];
        s4[idx] = bn_prelu(acc, cb, bg, bb, bm, bv, pa, 3);
    }
    __syncthreads();

    if (tid < 256) {
        int r = tid >> 4, c = tid & 15;
        const float* w = cw + 4 * 9;
        float acc = 0.0f;
        #pragma unroll
        for (int di = 0; di < 3; ++di)
            #pragma unroll
            for (int dj = 0; dj < 3; ++dj)
                acc += s4[(3 * r + dj) * 50 + (3 * c + di)] * w[di * 3 + dj];
        s5[tid] = bn_prelu(acc, cb, bg, bb, bm, bv, pa, 4);
    }
    __syncthreads();

    if (tid < 256) {
        int m = tid >> 4, n = tid & 15;
        sx[tid] = s5[n * 16 + m];
    }
    __syncthreads();

    if (tid < 82) {
        float acc = b5[tid];
        for (int k = 0; k < 256; ++k) acc += sx[k] * w5[k * 82 + tid];
        h[tid] = acc;
    }
    __syncthreads();
    if (tid == 0) {
        float mu = 0.0f;
        for (int o = 0; o < 82; ++o) mu += h[o];
        mu *= (1.0f / 82.0f);
        float var = 0.0f;
        for (int o = 0; o < 82; ++o) { float d = h[o] - mu; var += d * d; }
        var *= (1.0f / 82.0f);
        red[0] = mu;
        red[1] = rsqrtf(var + 1e-5f);
    }
    __syncthreads();
    if (tid < 82) {
        float v = (h[tid] - red[0]) * red[1] * lg[tid] + lb[tid];
        float a = p5a[0];
        h[tid] = v >= 0.0f ? v : a * v;
    }
    __syncthreads();
    if (tid < 5) {
        float acc = b6[tid];
        for (int o = 0; o < 82; ++o) acc += h[o] * w6[o * 5 + tid];
        out[tid] = acc;
    }
}

// ---------------------------------------------------------------------------
extern "C" void kernel_launch(void* const* d_in, const int* in_sizes, int n_in,
                              void* d_out, int out_size, void* d_ws, size_t ws_size,
                              hipStream_t stream)
{
    const float* xr  = (const float*)d_in[0];
    const float* xi  = (const float*)d_in[1];
    const float* mk  = (const float*)d_in[2];
    const float* pk  = (const float*)d_in[3];
    const float* cw  = (const float*)d_in[4];
    const float* cb  = (const float*)d_in[5];
    const float* bg  = (const float*)d_in[6];
    const float* bb  = (const float*)d_in[7];
    const float* bm  = (const float*)d_in[8];
    const float* bv  = (const float*)d_in[9];
    const float* pa  = (const float*)d_in[10];
    const float* w5  = (const float*)d_in[11];
    const float* b5  = (const float*)d_in[12];
    const float* lg  = (const float*)d_in[13];
    const float* lb  = (const float*)d_in[14];
    const float* p5a = (const float*)d_in[15];
    const float* w6  = (const float*)d_in[16];
    const float* b6  = (const float*)d_in[17];
    float* outp = (float*)d_out;

    char* ws = (char*)d_ws;
    const size_t Q = (size_t)64 * 1024 * 1024;
    __half2* A = (__half2*)ws;                 // 64 MB: row-FFT result (half2)
    __half2* B = (__half2*)(ws + Q);           // 64 MB: transposed
    __half*  ximg = (__half*)(ws + 2 * Q);     // 32 MB: real image (transposed, fp16)
    float* c1 = (float*)ws;                    // reuse A's space
    float* c2 = c1 + 1365 * 1365;
    float* c3 = c2 + 455 * 455;

    k_fft_rows_fused<<<N, TPB, 0, stream>>>(xr, xi, mk, pk, A);
    k_transpose<<<dim3(N / 32, N / 32), dim3(32, 8), 0, stream>>>(
        (const unsigned int*)A, (unsigned int*)B);
    k_fft_rows_final<<<N, TPB, 0, stream>>>(B, ximg);

    k_conv_h0<<<(1365 * 1365 + 255) / 256, 256, 0, stream>>>(ximg, c1,
        cw, cb, bg, bb, bm, bv, pa);
    k_conv<<<(455 * 455 + 255) / 256, 256, 0, stream>>>(c1, c2, 1365, 455,
        cw, cb, bg, bb, bm, bv, pa, 1);
    k_conv<<<(151 * 151 + 255) / 256, 256, 0, stream>>>(c2, c3, 455, 151,
        cw, cb, bg, bb, bm, bv, pa, 2);

    k_tail<<<1, 1024, 0, stream>>>(c3, cw, cb, bg, bb, bm, bv, pa,
                                   w5, b5, lg, lb, p5a, w6, b6, outp);
}

// Round 5
// 376.258 us; speedup vs baseline: 1.4512x; 1.4512x over previous
//
#include <hip/hip_runtime.h>
#include <hip/hip_fp16.h>
#include <math.h>

#define N 4096
#define TPB 256
#define PI2_F 6.283185307179586f
#define PAD(i) ((i) + ((i) >> 4))   // bank-spread for 4B LDS elements

__device__ __forceinline__ float2 cmul(float2 a, float2 b) {
    return make_float2(a.x * b.x - a.y * b.y, a.x * b.y + a.y * b.x);
}
__device__ __forceinline__ float2 cadd(float2 a, float2 b) { return make_float2(a.x + b.x, a.y + b.y); }
__device__ __forceinline__ float2 csub(float2 a, float2 b) { return make_float2(a.x - b.x, a.y - b.y); }
__device__ __forceinline__ float2 muli(float2 a) { return make_float2(-a.y, a.x); }   // +i * a (inverse)

// fast atan2: poly on t in [0,1], max err ~1e-5 rad.
__device__ __forceinline__ float fast_atan2f(float y, float x) {
    float ax = fabsf(x), ay = fabsf(y);
    float mx = fmaxf(ax, ay), mn = fminf(ax, ay);
    float t = mn * __builtin_amdgcn_rcpf(fmaxf(mx, 1e-37f));
    float s = t * t;
    float r = fmaf(s, fmaf(s, fmaf(s, fmaf(s, 0.0208351f, -0.0851330f),
                                    0.1801410f), -0.3302995f), 0.9998660f) * t;
    if (ay > ax) r = 1.5707963267948966f - r;
    if (x < 0.0f) r = 3.1415926535897932f - r;
    return copysignf(r, y);
}

// 16-point inverse DFT, in-place, natural order. Two radix-4 stages.
__device__ __forceinline__ void ifft16(float2 v[16]) {
    const float C1 = 0.9238795325112867f, S1 = 0.3826834323650898f;
    const float C2 = 0.7071067811865476f;
    float2 y[16];
    #pragma unroll
    for (int t = 0; t < 4; ++t) {
        float2 a0 = v[t], a1 = v[t + 4], a2 = v[t + 8], a3 = v[t + 12];
        float2 t0 = cadd(a0, a2), t1 = csub(a0, a2);
        float2 t2 = cadd(a1, a3), t3 = muli(csub(a1, a3));
        float2 c0 = cadd(t0, t2), c1 = cadd(t1, t3);
        float2 c2 = csub(t0, t2), c3 = csub(t1, t3);
        if (t == 0) {
            y[0] = c0; y[1] = c1; y[2] = c2; y[3] = c3;
        } else if (t == 1) {
            y[4] = c0;
            y[5] = cmul(c1, make_float2(C1, S1));
            y[6] = cmul(c2, make_float2(C2, C2));
            y[7] = cmul(c3, make_float2(S1, C1));
        } else if (t == 2) {
            y[8] = c0;
            y[9]  = cmul(c1, make_float2(C2, C2));
            y[10] = muli(c2);
            y[11] = cmul(c3, make_float2(-C2, C2));
        } else {
            y[12] = c0;
            y[13] = cmul(c1, make_float2(S1, C1));
            y[14] = cmul(c2, make_float2(-C2, C2));
            y[15] = cmul(c3, make_float2(-C1, -S1));
        }
    }
    #pragma unroll
    for (int t = 0; t < 4; ++t) {
        float2 a0 = y[t], a1 = y[t + 4], a2 = y[t + 8], a3 = y[t + 12];
        float2 t0 = cadd(a0, a2), t1 = csub(a0, a2);
        float2 t2 = cadd(a1, a3), t3 = muli(csub(a1, a3));
        v[t]      = cadd(t0, t2);
        v[t + 4]  = cadd(t1, t3);
        v[t + 8]  = csub(t0, t2);
        v[t + 12] = csub(t1, t3);
    }
}

// ---------------------------------------------------------------------------
// Pass 1: fused (mag/phase -> complex) + 4096-pt row inverse FFT.
// fp16 LDS exchanges (17 KB). launch_bounds(256,4): compiler allocates ~64
// VGPRs naturally (NO spills); HW can still fit 8 blocks/CU at 64 VGPR.
// ---------------------------------------------------------------------------
__global__ __launch_bounds__(TPB, 4) void k_fft_rows_fused(
    const float* __restrict__ xr, const float* __restrict__ xi,
    const float* __restrict__ mk, const float* __restrict__ pk,
    __half2* __restrict__ out)
{
    __shared__ __half2 lds[4096 + 256];
    const int t = threadIdx.x;
    const size_t base = (size_t)blockIdx.x * N;
    float2 v[16];

    #pragma unroll
    for (int q = 0; q < 16; ++q) {
        int idx = t + 256 * q;
        float a = xr[base + idx];
        float b = xi[base + idx];
        float mag = sqrtf(a * a + b * b) * mk[base + idx];
        float ph  = fast_atan2f(b, a) * pk[base + idx];
        float s, c;
        __sincosf(ph, &s, &c);
        v[q] = make_float2(mag * c, mag * s);
    }

    // stage 0: m=1, j=t, twiddle W4096^{p*t}, dst = 16t+p
    ifft16(v);
    {
        float s1, c1;
        __sincosf(PI2_F * (float)t * (1.0f / 4096.0f), &s1, &c1);
        float2 w1 = make_float2(c1, s1);
        float2 w = make_float2(1.0f, 0.0f);
        #pragma unroll
        for (int p = 0; p < 16; ++p) {
            float2 z = cmul(v[p], w);
            lds[PAD(16 * t + p)] = __floats2half2_rn(z.x, z.y);
            w = cmul(w, w1);
        }
    }
    __syncthreads();
    #pragma unroll
    for (int q = 0; q < 16; ++q) v[q] = __half22float2(lds[PAD(t + 256 * q)]);
    __syncthreads();

    // stage 1: m=16, j=t>>4, k=t&15, twiddle W256^{p*j}, dst = j*256+k+16p
    ifft16(v);
    {
        int j = t >> 4, k = t & 15;
        float s1, c1;
        __sincosf(PI2_F * (float)j * (1.0f / 256.0f), &s1, &c1);
        float2 w1 = make_float2(c1, s1);
        float2 w = make_float2(1.0f, 0.0f);
        int dbase = j * 256 + k;
        #pragma unroll
        for (int p = 0; p < 16; ++p) {
            float2 z = cmul(v[p], w);
            lds[PAD(dbase + 16 * p)] = __floats2half2_rn(z.x, z.y);
            w = cmul(w, w1);
        }
    }
    __syncthreads();
    #pragma unroll
    for (int q = 0; q < 16; ++q) v[q] = __half22float2(lds[PAD(t + 256 * q)]);

    // stage 2: m=256, no twiddle, dst = t + 256p
    ifft16(v);
    const float S = 1.0f / 4096.0f;
    #pragma unroll
    for (int p = 0; p < 16; ++p)
        out[base + t + 256 * p] = __floats2half2_rn(v[p].x * S, v[p].y * S);
}

// ---------------------------------------------------------------------------
// Tiled transpose of 4096x4096 half2 (4-byte elements)
// ---------------------------------------------------------------------------
__global__ void k_transpose(const unsigned int* __restrict__ in,
                            unsigned int* __restrict__ out)
{
    __shared__ unsigned int tile[32][33];
    const int bx = blockIdx.x * 32, by = blockIdx.y * 32;
    const int tx = threadIdx.x, ty = threadIdx.y;   // block (32,8)
    #pragma unroll
    for (int k = 0; k < 4; ++k)
        tile[ty + k * 8][tx] = in[(size_t)(by + ty + k * 8) * N + bx + tx];
    __syncthreads();
    #pragma unroll
    for (int k = 0; k < 4; ++k)
        out[(size_t)(bx + ty + k * 8) * N + by + tx] = tile[tx][ty + k * 8];
}

// ---------------------------------------------------------------------------
// Pass 2: row FFT on transposed half2 array (= column FFT); real part out
// (fp16) with ifftshift sign (-1)^(row+t) and the second 1/4096 scale.
// ---------------------------------------------------------------------------
__global__ __launch_bounds__(TPB, 4) void k_fft_rows_final(
    const __half2* __restrict__ in, __half* __restrict__ out)
{
    __shared__ __half2 lds[4096 + 256];
    const int t = threadIdx.x;
    const int row = blockIdx.x;
    const size_t base = (size_t)row * N;
    float2 v[16];

    #pragma unroll
    for (int q = 0; q < 16; ++q) v[q] = __half22float2(in[base + t + 256 * q]);

    ifft16(v);
    {
        float s1, c1;
        __sincosf(PI2_F * (float)t * (1.0f / 4096.0f), &s1, &c1);
        float2 w1 = make_float2(c1, s1);
        float2 w = make_float2(1.0f, 0.0f);
        #pragma unroll
        for (int p = 0; p < 16; ++p) {
            float2 z = cmul(v[p], w);
            lds[PAD(16 * t + p)] = __floats2half2_rn(z.x, z.y);
            w = cmul(w, w1);
        }
    }
    __syncthreads();
    #pragma unroll
    for (int q = 0; q < 16; ++q) v[q] = __half22float2(lds[PAD(t + 256 * q)]);
    __syncthreads();

    ifft16(v);
    {
        int j = t >> 4, k = t & 15;
        float s1, c1;
        __sincosf(PI2_F * (float)j * (1.0f / 256.0f), &s1, &c1);
        float2 w1 = make_float2(c1, s1);
        float2 w = make_float2(1.0f, 0.0f);
        int dbase = j * 256 + k;
        #pragma unroll
        for (int p = 0; p < 16; ++p) {
            float2 z = cmul(v[p], w);
            lds[PAD(dbase + 16 * p)] = __floats2half2_rn(z.x, z.y);
            w = cmul(w, w1);
        }
    }
    __syncthreads();
    #pragma unroll
    for (int q = 0; q < 16; ++q) v[q] = __half22float2(lds[PAD(t + 256 * q)]);

    ifft16(v);

    const float scale = 1.0f / 4096.0f;
    const float sgn = ((row + t) & 1) ? -scale : scale;
    #pragma unroll
    for (int p = 0; p < 16; ++p)
        out[base + t + 256 * p] = __float2half_rn(v[p].x * sgn);
}

// ---------------------------------------------------------------------------
// Conv + BN + PReLU (transposed taps). Layer 0 reads fp16 image.
// ---------------------------------------------------------------------------
__device__ __forceinline__ float bn_prelu(float acc,
    const float* __restrict__ cb, const float* __restrict__ bg,
    const float* __restrict__ bb, const float* __restrict__ bm,
    const float* __restrict__ bv, const float* __restrict__ pa, int layer)
{
    float g  = bg[layer];
    float rs = rsqrtf(bv[layer] + 1e-5f);
    float v = (acc + cb[layer]) * (g * rs) + (bb[layer] - g * bm[layer] * rs);
    float a = pa[layer];
    return v >= 0.0f ? v : a * v;
}

__global__ void k_conv_h0(const __half* __restrict__ in, float* __restrict__ out,
                          const float* __restrict__ cw, const float* __restrict__ cb,
                          const float* __restrict__ bg, const float* __restrict__ bb,
                          const float* __restrict__ bm, const float* __restrict__ bv,
                          const float* __restrict__ pa)
{
    const int wout = 1365, win = 4096;
    int idx = blockIdx.x * blockDim.x + threadIdx.x;
    if (idx >= wout * wout) return;
    int r = idx / wout, c = idx % wout;
    const float* w = cw;
    float acc = 0.0f;
    #pragma unroll
    for (int di = 0; di < 3; ++di)
        #pragma unroll
        for (int dj = 0; dj < 3; ++dj)
            acc += __half2float(in[(size_t)(3 * r + dj) * win + (3 * c + di)]) * w[di * 3 + dj];
    out[idx] = bn_prelu(acc, cb, bg, bb, bm, bv, pa, 0);
}

__global__ void k_conv(const float* __restrict__ in, float* __restrict__ out,
                       int win, int wout,
                       const float* __restrict__ cw, const float* __restrict__ cb,
                       const float* __restrict__ bg, const float* __restrict__ bb,
                       const float* __restrict__ bm, const float* __restrict__ bv,
                       const float* __restrict__ pa, int layer)
{
    int idx = blockIdx.x * blockDim.x + threadIdx.x;
    if (idx >= wout * wout) return;
    int r = idx / wout, c = idx % wout;
    const float* w = cw + layer * 9;
    float acc = 0.0f;
    #pragma unroll
    for (int di = 0; di < 3; ++di)
        #pragma unroll
        for (int dj = 0; dj < 3; ++dj)
            acc += in[(size_t)(3 * r + dj) * win + (3 * c + di)] * w[di * 3 + dj];
    out[idx] = bn_prelu(acc, cb, bg, bb, bm, bv, pa, layer);
}

// ---------------------------------------------------------------------------
// Tail: conv4 (151->50) + conv5 (50->16) + head, one block of 1024 threads.
// ---------------------------------------------------------------------------
__global__ __launch_bounds__(1024) void k_tail(
    const float* __restrict__ c3img,
    const float* __restrict__ cw, const float* __restrict__ cb,
    const float* __restrict__ bg, const float* __restrict__ bb,
    const float* __restrict__ bm, const float* __restrict__ bv,
    const float* __restrict__ pa,
    const float* __restrict__ w5, const float* __restrict__ b5,
    const float* __restrict__ lg, const float* __restrict__ lb,
    const float* __restrict__ p5a,
    const float* __restrict__ w6, const float* __restrict__ b6,
    float* __restrict__ out)
{
    __shared__ float s4[2500];
    __shared__ float s5[256];
    __shared__ float sx[256];
    __shared__ float h[82];
    __shared__ float red[2];
    const int tid = threadIdx.x;

    for (int idx = tid; idx < 2500; idx += 1024) {
        int r = idx / 50, c = idx % 50;
        const float* w = cw + 3 * 9;
        float acc = 0.0f;
        #pragma unroll
        for (int di = 0; di < 3; ++di)
            #pragma unroll
            for (int dj = 0; dj < 3; ++dj)
                acc += c3img[(size_t)(3 * r + dj) * 151 + (3 * c + di)] * w[di * 3 + dj];
        s4[idx] = bn_prelu(acc, cb, bg, bb, bm, bv, pa, 3);
    }
    __syncthreads();

    if (tid < 256) {
        int r = tid >> 4, c = tid & 15;
        const float* w = cw + 4 * 9;
        float acc = 0.0f;
        #pragma unroll
        for (int di = 0; di < 3; ++di)
            #pragma unroll
            for (int dj = 0; dj < 3; ++dj)
                acc += s4[(3 * r + dj) * 50 + (3 * c + di)] * w[di * 3 + dj];
        s5[tid] = bn_prelu(acc, cb, bg, bb, bm, bv, pa, 4);
    }
    __syncthreads();

    if (tid < 256) {
        int m = tid >> 4, n = tid & 15;
        sx[tid] = s5[n * 16 + m];
    }
    __syncthreads();

    if (tid < 82) {
        float acc = b5[tid];
        for (int k = 0; k < 256; ++k) acc += sx[k] * w5[k * 82 + tid];
        h[tid] = acc;
    }
    __syncthreads();
    if (tid == 0) {
        float mu = 0.0f;
        for (int o = 0; o < 82; ++o) mu += h[o];
        mu *= (1.0f / 82.0f);
        float var = 0.0f;
        for (int o = 0; o < 82; ++o) { float d = h[o] - mu; var += d * d; }
        var *= (1.0f / 82.0f);
        red[0] = mu;
        red[1] = rsqrtf(var + 1e-5f);
    }
    __syncthreads();
    if (tid < 82) {
        float v = (h[tid] - red[0]) * red[1] * lg[tid] + lb[tid];
        float a = p5a[0];
        h[tid] = v >= 0.0f ? v : a * v;
    }
    __syncthreads();
    if (tid < 5) {
        float acc = b6[tid];
        for (int o = 0; o < 82; ++o) acc += h[o] * w6[o * 5 + tid];
        out[tid] = acc;
    }
}

// ---------------------------------------------------------------------------
extern "C" void kernel_launch(void* const* d_in, const int* in_sizes, int n_in,
                              void* d_out, int out_size, void* d_ws, size_t ws_size,
                              hipStream_t stream)
{
    const float* xr  = (const float*)d_in[0];
    const float* xi  = (const float*)d_in[1];
    const float* mk  = (const float*)d_in[2];
    const float* pk  = (const float*)d_in[3];
    const float* cw  = (const float*)d_in[4];
    const float* cb  = (const float*)d_in[5];
    const float* bg  = (const float*)d_in[6];
    const float* bb  = (const float*)d_in[7];
    const float* bm  = (const float*)d_in[8];
    const float* bv  = (const float*)d_in[9];
    const float* pa  = (const float*)d_in[10];
    const float* w5  = (const float*)d_in[11];
    const float* b5  = (const float*)d_in[12];
    const float* lg  = (const float*)d_in[13];
    const float* lb  = (const float*)d_in[14];
    const float* p5a = (const float*)d_in[15];
    const float* w6  = (const float*)d_in[16];
    const float* b6  = (const float*)d_in[17];
    float* outp = (float*)d_out;

    char* ws = (char*)d_ws;
    const size_t Q = (size_t)64 * 1024 * 1024;
    __half2* A = (__half2*)ws;                 // 64 MB: row-FFT result (half2)
    __half2* B = (__half2*)(ws + Q);           // 64 MB: transposed
    __half*  ximg = (__half*)(ws + 2 * Q);     // 32 MB: real image (transposed, fp16)
    float* c1 = (float*)ws;                    // reuse A's space
    float* c2 = c1 + 1365 * 1365;
    float* c3 = c2 + 455 * 455;

    k_fft_rows_fused<<<N, TPB, 0, stream>>>(xr, xi, mk, pk, A);
    k_transpose<<<dim3(N / 32, N / 32), dim3(32, 8), 0, stream>>>(
        (const unsigned int*)A, (unsigned int*)B);
    k_fft_rows_final<<<N, TPB, 0, stream>>>(B, ximg);

    k_conv_h0<<<(1365 * 1365 + 255) / 256, 256, 0, stream>>>(ximg, c1,
        cw, cb, bg, bb, bm, bv, pa);
    k_conv<<<(455 * 455 + 255) / 256, 256, 0, stream>>>(c1, c2, 1365, 455,
        cw, cb, bg, bb, bm, bv, pa, 1);
    k_conv<<<(151 * 151 + 255) / 256, 256, 0, stream>>>(c2, c3, 455, 151,
        cw, cb, bg, bb, bm, bv, pa, 2);

    k_tail<<<1, 1024, 0, stream>>>(c3, cw, cb, bg, bb, bm, bv, pa,
                                   w5, b5, lg, lb, p5a, w6, b6, outp);
}